// Round 7
// baseline (38.852 us; speedup 1.0000x reference)
//
#include <hip/hip_runtime.h>

#define B_ 2
#define C_ 256
#define HW_ 64
#define N_ 4096
#define K_SEL 1228   // int(4096*0.3)
#define MIP_ 16

__device__ __forceinline__ float sigm(float z) { return 1.0f / (1.0f + expf(-z)); }

// ---------------------------------------------------------------- k_att
// One block per (b,seg,pos). Computes r[o] = conv1(pool(x))[b,seg,pos,o]
// directly from x (conv and pooling commute), then BN+ReLU+attention dots
// + sigmoids. seg 0: row pos (mean over w) -> ahb,sdb. seg 1: col pos
// (mean over h) -> swb.
__global__ __launch_bounds__(256) void k_att(
    const float* __restrict__ x,
    const float* __restrict__ w1, const float* __restrict__ b1,
    const float* __restrict__ gam, const float* __restrict__ bet,
    const float* __restrict__ mea, const float* __restrict__ var,
    const float* __restrict__ wh, const float* __restrict__ bh,
    const float* __restrict__ ww, const float* __restrict__ bw,
    const float* __restrict__ wd1, const float* __restrict__ bd1,
    const float* __restrict__ wd2, const float* __restrict__ bd2,
    float* __restrict__ ahb, float* __restrict__ swb, float* __restrict__ sdb) {
  __shared__ float w1T[C_][MIP_];     // transposed weights, 16KB
  __shared__ float qpart[MIP_][4];
  __shared__ float rsh[MIP_];
  int blk = blockIdx.x, t = threadIdx.x;
  int pos = blk & 63, seg = (blk >> 6) & 1, b = blk >> 7;
  int wv = t >> 6, l = t & 63;

  // stage w1 transposed (coalesced global read)
  #pragma unroll
  for (int i = 0; i < 16; ++i) {
    int idx = i * 256 + t;
    w1T[idx & 255][idx >> 8] = w1[idx];
  }
  __syncthreads();

  float g[MIP_];
  #pragma unroll
  for (int o = 0; o < MIP_; ++o) g[o] = 0.0f;

  const float* xb = x + (size_t)b * C_ * N_;
  if (seg == 0) {
    // row pos: lane = w, wave = c-quarter; coalesced 256B loads per c
    const float* base = xb + pos * 64 + l;
    int c0 = wv * 64;
    #pragma unroll 4
    for (int ci = 0; ci < 64; ++ci) {
      int c = c0 + ci;
      float xv = base[c * N_];
      float4 wa = *(const float4*)&w1T[c][0];
      float4 wb4 = *(const float4*)&w1T[c][4];
      float4 wc = *(const float4*)&w1T[c][8];
      float4 wd = *(const float4*)&w1T[c][12];
      g[0] = fmaf(wa.x, xv, g[0]);  g[1] = fmaf(wa.y, xv, g[1]);
      g[2] = fmaf(wa.z, xv, g[2]);  g[3] = fmaf(wa.w, xv, g[3]);
      g[4] = fmaf(wb4.x, xv, g[4]); g[5] = fmaf(wb4.y, xv, g[5]);
      g[6] = fmaf(wb4.z, xv, g[6]); g[7] = fmaf(wb4.w, xv, g[7]);
      g[8] = fmaf(wc.x, xv, g[8]);  g[9] = fmaf(wc.y, xv, g[9]);
      g[10] = fmaf(wc.z, xv, g[10]); g[11] = fmaf(wc.w, xv, g[11]);
      g[12] = fmaf(wd.x, xv, g[12]); g[13] = fmaf(wd.y, xv, g[13]);
      g[14] = fmaf(wd.z, xv, g[14]); g[15] = fmaf(wd.w, xv, g[15]);
    }
  } else {
    // col pos: thread's channel c = t; accumulate over h in-register
    const float* base = xb + (size_t)t * N_ + pos;
    float xwv = 0.0f;
    #pragma unroll 8
    for (int h = 0; h < 64; ++h) xwv += base[h * 64];
    #pragma unroll
    for (int o = 0; o < MIP_; ++o) g[o] = w1T[t][o] * xwv;
  }

  // reduce g[o] over all 256 threads: wave shfl + LDS combine
  #pragma unroll
  for (int o = 0; o < MIP_; ++o) {
    float s = g[o];
    #pragma unroll
    for (int off = 32; off; off >>= 1) s += __shfl_xor(s, off, 64);
    if (l == 0) qpart[o][wv] = s;
  }
  __syncthreads();

  if (t < MIP_) {
    float r = (qpart[t][0] + qpart[t][1] + qpart[t][2] + qpart[t][3]) *
              (1.0f / 64.0f);
    float sc = gam[t] * rsqrtf(var[t] + 1e-5f);
    float y = r + b1[t] - mea[t];
    rsh[t] = fmaxf(fmaf(y, sc, bet[t]), 0.0f);
  }
  __syncthreads();

  if (t == 0) {
    float aH = bh[0], aW = bw[0], aD1 = bd1[0], aD2 = bd2[0];
    #pragma unroll
    for (int o = 0; o < MIP_; ++o) {
      float rr = rsh[o];
      aH = fmaf(wh[o], rr, aH);
      aW = fmaf(ww[o], rr, aW);
      aD1 = fmaf(wd1[o], rr, aD1);
      aD2 = fmaf(wd2[o], rr, aD2);
    }
    if (seg == 0) {
      ahb[b * HW_ + pos] = sigm(aH);
      sdb[b * HW_ + pos] = sigm(aD1) * sigm(aD2);
    } else {
      swb[b * HW_ + pos] = sigm(aW);
    }
  }
}

// ---------------------------------------------------------------- k_fin
// One block per (b,c). Redundantly (but in parallel) redoes the selection:
// products 16/thread in regs, bit-bisection for k-th largest (8192-ULP stop),
// q-moments; then P-moments over register-prefetched x, and the output.
__global__ __launch_bounds__(256) void k_fin(
    const float* __restrict__ x,
    const float* __restrict__ ahb, const float* __restrict__ swb,
    const float* __restrict__ sdb, const float* __restrict__ msk,
    float* __restrict__ out) {
  __shared__ float ahs[HW_], sps[HW_];
  __shared__ int icomb[4];
  __shared__ float fmn[4], fmx[4];
  __shared__ float red[15][4];
  __shared__ float ps[15];
  int bc = blockIdx.x, b = bc >> 8, t = threadIdx.x;
  const float* xr = x + (size_t)bc * N_;

  // prefetch x (16 values) — latency hides under selection phase
  float4 xv[4];
  #pragma unroll
  for (int it = 0; it < 4; ++it)
    xv[it] = *(const float4*)&xr[it * 1024 + t * 4];

  if (t < HW_) {
    ahs[t] = ahb[b * HW_ + t];
    sps[t] = swb[b * HW_ + t] * sdb[b * HW_ + t];
  }
  __syncthreads();

  // unified index map: j = it*1024 + 4t + e  ->  h = it*16 + (t>>4), w = (4t+e)&63
  float4 sp4 = *(const float4*)&sps[(t * 4) & 63];
  const float spe[4] = {sp4.x, sp4.y, sp4.z, sp4.w};
  float ahv[4];
  #pragma unroll
  for (int it = 0; it < 4; ++it) ahv[it] = ahs[it * 16 + (t >> 4)];

  float v[16];
  #pragma unroll
  for (int it = 0; it < 4; ++it)
    #pragma unroll
    for (int e = 0; e < 4; ++e) v[it * 4 + e] = ahv[it] * spe[e];

  // global min / max (positive floats: float order == bit order)
  float mn = v[0], mx = v[0];
  #pragma unroll
  for (int k = 1; k < 16; ++k) { mn = fminf(mn, v[k]); mx = fmaxf(mx, v[k]); }
  #pragma unroll
  for (int o = 32; o; o >>= 1) {
    mn = fminf(mn, __shfl_xor(mn, o, 64));
    mx = fmaxf(mx, __shfl_xor(mx, o, 64));
  }
  if ((t & 63) == 0) { fmn[t >> 6] = mn; fmx[t >> 6] = mx; }
  __syncthreads();
  mn = fminf(fminf(fmn[0], fmn[1]), fminf(fmn[2], fmn[3]));
  mx = fmaxf(fmaxf(fmx[0], fmx[1]), fmaxf(fmx[2], fmx[3]));

  unsigned lo = __float_as_uint(mn);        // cnt_ge(lo) = 4096 >= K
  unsigned hi = __float_as_uint(mx) + 1u;   // cnt_ge(hi) = 0 < K
  while (hi - lo > 8192u) {
    unsigned mid = lo + ((hi - lo) >> 1);
    float midf = __uint_as_float(mid);
    int cnt = 0;
    #pragma unroll
    for (int k = 0; k < 16; ++k) cnt += (v[k] >= midf) ? 1 : 0;
    #pragma unroll
    for (int o = 32; o; o >>= 1) cnt += __shfl_xor(cnt, o, 64);
    if ((t & 63) == 0) icomb[t >> 6] = cnt;
    __syncthreads();
    int total = icomb[0] + icomb[1] + icomb[2] + icomb[3];
    __syncthreads();
    if (total >= K_SEL) lo = mid; else hi = mid;
  }
  float thr = __uint_as_float(lo);
  float gm = sigm(msk[0]);

  // acc[0..6] = q1..q7 (from f over S), acc[7] = T, acc[8..14] = P1..P7
  float acc[15];
  #pragma unroll
  for (int m = 0; m < 15; ++m) acc[m] = 0.0f;
  #pragma unroll
  for (int it = 0; it < 4; ++it) {
    const float xe[4] = {xv[it].x, xv[it].y, xv[it].z, xv[it].w};
    #pragma unroll
    for (int e = 0; e < 4; ++e) {
      float vv = v[it * 4 + e];
      float xx = xe[e];
      acc[7] += xx;
      if (vv >= thr) {
        float p = vv;
        acc[0] += p;
        acc[8] = fmaf(p, xx, acc[8]); p *= vv;
        acc[1] += p;
        acc[9] = fmaf(p, xx, acc[9]); p *= vv;
        acc[2] += p;
        acc[10] = fmaf(p, xx, acc[10]); p *= vv;
        acc[3] += p;
        acc[11] = fmaf(p, xx, acc[11]); p *= vv;
        acc[4] += p;
        acc[12] = fmaf(p, xx, acc[12]); p *= vv;
        acc[5] += p;
        acc[13] = fmaf(p, xx, acc[13]); p *= vv;
        acc[6] += p;
        acc[14] = fmaf(p, xx, acc[14]);
      }
    }
  }
  #pragma unroll
  for (int m = 0; m < 15; ++m) {
    float s = acc[m];
    #pragma unroll
    for (int o = 32; o; o >>= 1) s += __shfl_xor(s, o, 64);
    if ((t & 63) == 0) red[m][t >> 6] = s;
  }
  __syncthreads();
  if (t < 15) {
    // scale: q_m and P_m by 1/m! (T unscaled)
    const float invf[15] = {1.0f, 0.5f, 1.0f / 6.0f, 1.0f / 24.0f,
                            1.0f / 120.0f, 1.0f / 720.0f, 1.0f / 5040.0f,
                            1.0f,
                            1.0f, 0.5f, 1.0f / 6.0f, 1.0f / 24.0f,
                            1.0f / 120.0f, 1.0f / 720.0f, 1.0f / 5040.0f};
    ps[t] = (red[t][0] + red[t][1] + red[t][2] + red[t][3]) * invf[t];
  }
  __syncthreads();
  float q1 = ps[0], q2 = ps[1], q3 = ps[2], q4 = ps[3];
  float q5 = ps[4], q6 = ps[5], q7 = ps[6];
  float T = ps[7];
  float p1 = ps[8], p2 = ps[9], p3 = ps[10], p4 = ps[11];
  float p5 = ps[12], p6 = ps[13], p7 = ps[14];

  float* ob = out + (size_t)bc * N_;
  #pragma unroll
  for (int it = 0; it < 4; ++it) {
    float o4[4];
    #pragma unroll
    for (int e = 0; e < 4; ++e) {
      float alpha = gm * v[it * 4 + e];
      float hn = p7;
      hn = fmaf(alpha, hn, p6);
      hn = fmaf(alpha, hn, p5);
      hn = fmaf(alpha, hn, p4);
      hn = fmaf(alpha, hn, p3);
      hn = fmaf(alpha, hn, p2);
      hn = fmaf(alpha, hn, p1);
      float numer = fmaf(alpha, hn, T);
      float hd = q7;
      hd = fmaf(alpha, hd, q6);
      hd = fmaf(alpha, hd, q5);
      hd = fmaf(alpha, hd, q4);
      hd = fmaf(alpha, hd, q3);
      hd = fmaf(alpha, hd, q2);
      hd = fmaf(alpha, hd, q1);
      float denom = fmaf(alpha, hd, (float)N_);
      o4[e] = numer / denom;
    }
    *(float4*)&ob[it * 1024 + t * 4] = make_float4(o4[0], o4[1], o4[2], o4[3]);
  }
}

extern "C" void kernel_launch(void* const* d_in, const int* in_sizes, int n_in,
                              void* d_out, int out_size, void* d_ws, size_t ws_size,
                              hipStream_t stream) {
  (void)in_sizes; (void)n_in; (void)out_size; (void)ws_size;
  const float* x   = (const float*)d_in[0];
  const float* w1  = (const float*)d_in[1];
  const float* b1  = (const float*)d_in[2];
  const float* gam = (const float*)d_in[3];
  const float* bet = (const float*)d_in[4];
  const float* mea = (const float*)d_in[5];
  const float* var = (const float*)d_in[6];
  const float* wh  = (const float*)d_in[7];
  const float* bh  = (const float*)d_in[8];
  const float* ww  = (const float*)d_in[9];
  const float* bw  = (const float*)d_in[10];
  const float* wd1 = (const float*)d_in[11];
  const float* bd1 = (const float*)d_in[12];
  const float* wd2 = (const float*)d_in[13];
  const float* bd2 = (const float*)d_in[14];
  const float* msk = (const float*)d_in[15];
  float* out = (float*)d_out;

  float* ws  = (float*)d_ws;
  float* ahb = ws;          // 128 floats
  float* swb = ws + 128;    // 128
  float* sdb = ws + 256;    // 128

  hipLaunchKernelGGL(k_att, dim3(B_ * 2 * HW_), dim3(256), 0, stream,
                     x, w1, b1, gam, bet, mea, var,
                     wh, bh, ww, bw, wd1, bd1, wd2, bd2, ahb, swb, sdb);
  hipLaunchKernelGGL(k_fin, dim3(B_ * C_), dim3(256), 0, stream,
                     x, ahb, swb, sdb, msk, out);
}